// Round 8
// baseline (95.152 us; speedup 1.0000x reference)
//
#include <hip/hip_runtime.h>
#include <cstdint>

#define BB     4096
#define TT     96
#define NC     85
#define BLANKC 84
#define DD     64
#define ALPHA  0.05f
#define BT     (BB * TT)      // 393216
#define NF4    (TT * NC / 4)  // 2040 float4 per batch row
#define NBLK   512            // fused-kernel blocks (2/CU)
#define RPB    (BB / NBLK)    // 8 batch rows per block
#define FSTR   73             // F-array row stride (odd-ish: spreads banks)

// ---------------------------------------------------------------------------
// Kernel 1 (fused, persistent): per block, loop over 8 batch rows with a
// one-row-ahead register pipeline:
//   A:sync  B: commit preds regs->LDS rows, raw labels->lab_ls, ISSUE next
//   row's preds+labels loads  C:sync  D: quarter-scan rows -> sv/sc, 12 thr
//   precompute per-step dup flags from raw labels  E:sync  F: thr t<96
//   combines quarters for t AND t+1 (strict > keeps lowest col), CTC mask,
//   finalize lab_ls, LDS histogram  G:sync  H: 12 feature steps — wave w owns
//   dims w*8..w*8+7, lanes = 8 positions x 8 dims; all 8 waves write disjoint
//   columns of ONE shared F[85][73]: plain += when step's 8 labels distinct,
//   wave-uniform LDS-atomic fallback otherwise (dupflag).
// Epilogue: F -> updp[blk], hist -> hpartT[class][blk], |f|^2 -> lossp[blk].
// LDS ~61 KB -> 2 blocks/CU; NO global atomics; labm never touches HBM.
// ---------------------------------------------------------------------------
template<int C0, int C1>
__device__ inline void scanR(const float* __restrict__ row, float& bv, int& bc) {
    bv = row[C0]; bc = C0;
#pragma unroll
    for (int c = C0 + 1; c < C1; ++c) {
        float v = row[c];
        if (v > bv) { bv = v; bc = c; }
    }
}

__global__ __launch_bounds__(512, 4) void k_fused(const float4* __restrict__ p4,
                                                  const int* __restrict__ labels,
                                                  const float* __restrict__ feat,
                                                  float* __restrict__ updp,
                                                  int* __restrict__ hpartT,
                                                  float* __restrict__ lossp,
                                                  float* __restrict__ out) {
    __shared__ float rows[TT * NC];                // 32640 B
    __shared__ float Farr[NC * FSTR];              // 24820 B
    __shared__ float sv[4 * TT];                   // 1536 B
    __shared__ int   sc[4 * TT];                   // 1536 B
    __shared__ unsigned lab_ls[TT];                // 384 B
    __shared__ int   dupflag[12];                  // 48 B
    __shared__ int   h[NC];                        // 340 B
    __shared__ float lred[8];

    int tid  = threadIdx.x;
    int blk  = blockIdx.x;
    int lane = tid & 63;
    int w    = tid >> 6;
    int sub  = lane >> 3;                          // position-in-octet
    int l8   = lane & 7;
    int dim  = (w << 3) | l8;                      // wave owns 8 dims

    for (int i = tid; i < NC * FSTR; i += 512) Farr[i] = 0.f;
    if (tid < NC) h[tid] = 0;
    if (blk == 0 && tid == 500) out[0] = 0.f;

    // prologue: issue row 0 loads
    int row0 = blk * RPB;
    const float4* s0 = p4 + (size_t)row0 * NF4;
    float4 v0 = s0[tid];
    float4 v1 = s0[tid + 512];
    float4 v2 = s0[tid + 1024];
    float4 v3 = s0[tid + 1536 < NF4 ? tid + 1536 : NF4 - 1];
    int lcur = (tid < TT) ? labels[row0 * TT + tid] : 0;
    float lsum = 0.f;

    for (int r8 = 0; r8 < RPB; ++r8) {
        int row = row0 + r8;
        __syncthreads();                           // A: prev row fully consumed
        // B: commit regs -> LDS, issue next row's loads
        float4* r4 = (float4*)rows;
        r4[tid]        = v0;
        r4[tid + 512]  = v1;
        r4[tid + 1024] = v2;
        if (tid + 1536 < NF4) r4[tid + 1536] = v3;
        if (tid < TT) lab_ls[tid] = (unsigned)lcur;
        int lnext = 0;
        if (r8 + 1 < RPB) {
            const float4* sn = p4 + (size_t)(row + 1) * NF4;
            v0 = sn[tid];
            v1 = sn[tid + 512];
            v2 = sn[tid + 1024];
            v3 = sn[tid + 1536 < NF4 ? tid + 1536 : NF4 - 1];
            if (tid < TT) lnext = labels[(row + 1) * TT + tid];
        }
        __syncthreads();                           // C: rows/lab_ls visible
        // D: quarter scan (q = wave>>1, uniform) + dup precompute
        {
            int q = tid >> 7, r = tid & 127;
            if (r < TT) {
                const float* rw = rows + r * NC;
                float bv; int bc;
                switch (q) {
                    case 0:  scanR< 0, 22>(rw, bv, bc); break;
                    case 1:  scanR<22, 43>(rw, bv, bc); break;
                    case 2:  scanR<43, 64>(rw, bv, bc); break;
                    default: scanR<64, 85>(rw, bv, bc); break;
                }
                sv[q * TT + r] = bv; sc[q * TT + r] = bc;
            }
            if (tid < 12) {
                int l[8];
#pragma unroll
                for (int k = 0; k < 8; ++k) l[k] = (int)lab_ls[tid * 8 + k];
                int d = 0;
#pragma unroll
                for (int a = 0; a < 8; ++a)
#pragma unroll
                    for (int b2 = a + 1; b2 < 8; ++b2) d |= (l[a] == l[b2]);
                dupflag[tid] = d;
            }
        }
        __syncthreads();                           // E: sv/sc/dupflag visible
        // F: combine t and t+1, mask, finalize lab_ls, histogram
        if (tid < TT) {
            int t1 = (tid + 1 < TT) ? tid + 1 : tid;
            float bv = sv[tid];  int bc = sc[tid];
            float bw = sv[t1];   int bd = sc[t1];
#pragma unroll
            for (int q = 1; q < 4; ++q) {
                float a = sv[q * TT + tid]; int c = sc[q * TT + tid];
                if (a > bv) { bv = a; bc = c; }
                float a1 = sv[q * TT + t1]; int c1 = sc[q * TT + t1];
                if (a1 > bw) { bw = a1; bd = c1; }
            }
            int m = (bc != BLANKC) && (tid == TT - 1 || bc != bd);
            lab_ls[tid] = (unsigned)lcur | ((unsigned)m << 31);
            atomicAdd(&h[lcur], m);                // LDS only
            lcur = lnext;
        }
        __syncthreads();                           // G: lab_ls final
        // H: 12 feature steps
        {
            const float* fb = feat + (size_t)row * TT * DD;
            int dfl[12];
#pragma unroll
            for (int k = 0; k < 12; ++k) dfl[k] = dupflag[k];
            float f = fb[sub * DD + dim];
#pragma unroll
            for (int s = 0; s < 12; ++s) {
                float fc = f;
                if (s < 11) f = fb[((s + 1) * 8 + sub) * DD + dim];
                unsigned lw = lab_ls[s * 8 + sub];
                float m = (float)(lw >> 31);
                int  la = (int)(lw & 0x7fffffffu);
                float c = m * fc;
                lsum = fmaf(c, fc, lsum);
                int a = la * FSTR + dim;
                if (dfl[s]) atomicAdd(&Farr[a], c);
                else        Farr[a] += c;
            }
        }
    }
    __syncthreads();
    // epilogue: flush F, histogram, loss partial
    float* myp = updp + (size_t)blk * (NC * DD);
    for (int i = tid; i < NC * DD; i += 512)
        myp[i] = Farr[(i >> 6) * FSTR + (i & 63)];
    if (tid < NC) hpartT[tid * NBLK + blk] = h[tid];
#pragma unroll
    for (int off = 32; off; off >>= 1) lsum += __shfl_xor(lsum, off);
    if (lane == 0) lred[w] = lsum;
    __syncthreads();
    if (tid == 0) {
        float s = 0.f;
#pragma unroll
        for (int ww = 0; ww < 8; ++ww) s += lred[ww];
        lossp[blk] = s;
    }
}

// ---------------------------------------------------------------------------
// Kernel 2: grid NC*4+1. Block (j,q): counts[j] = coalesced sum of
// hpartT[j][0..NBLK), then F over NBLK partials for 16 dims, write centers,
// atomic-add 0.5*loss piece into out[0]. Last block reduces Sfeat.
// ---------------------------------------------------------------------------
__global__ __launch_bounds__(256) void k_reduce(const float* __restrict__ updp,
                                                const float* __restrict__ lossp,
                                                const float* __restrict__ centers,
                                                const int* __restrict__ hpartT,
                                                float* __restrict__ out) {
    __shared__ float sred[256];
    __shared__ float sr[4];
    __shared__ int   scnt;
    int tid = threadIdx.x;
    int bid = blockIdx.x;
    if (bid < NC * 4) {
        int j = bid >> 2, q = bid & 3;
        int cs = 0;
        for (int t = tid; t < NBLK; t += 256) cs += hpartT[j * NBLK + t];
#pragma unroll
        for (int off = 32; off; off >>= 1) cs += __shfl_xor(cs, off);
        int lane = tid & 63, wv = tid >> 6;
        if (lane == 0) ((int*)sred)[wv] = cs;
        __syncthreads();
        if (tid == 0)
            scnt = ((int*)sred)[0] + ((int*)sred)[1] +
                   ((int*)sred)[2] + ((int*)sred)[3];
        __syncthreads();
        float cnt = (float)scnt;
        int i = tid & 15;
        int c16 = tid >> 4;
        int per = NBLK >> 4;                       // 32
        int col = j * DD + q * 16 + i;
        float s = 0.f;
        for (int b = c16 * per; b < (c16 + 1) * per; ++b)
            s += updp[(size_t)b * (NC * DD) + col];
        sred[tid] = s;
        __syncthreads();
        if (tid < 16) {
            float F = 0.f;
#pragma unroll
            for (int cc = 0; cc < 16; ++cc) F += sred[cc * 16 + i];
            float c   = centers[col];
            float scale = ALPHA / (1.f + cnt);
            out[1 + col] = c - scale * (cnt * c - F);
            float lp = cnt * c * c - 2.f * c * F;
#pragma unroll
            for (int off = 8; off; off >>= 1) lp += __shfl_xor(lp, off);
            if (i == 0) atomicAdd(&out[0], 0.5f * lp);
        }
    } else {
        float s = 0.f;
        for (int t = tid; t < NBLK; t += 256) s += lossp[t];
#pragma unroll
        for (int off = 32; off; off >>= 1) s += __shfl_xor(s, off);
        int lane = tid & 63, wv = tid >> 6;
        if (lane == 0) sr[wv] = s;
        __syncthreads();
        if (tid == 0) atomicAdd(&out[0], 0.5f * (sr[0] + sr[1] + sr[2] + sr[3]));
    }
}

// ---------------------------------------------------------------------------
extern "C" void kernel_launch(void* const* d_in, const int* in_sizes, int n_in,
                              void* d_out, int out_size, void* d_ws, size_t ws_size,
                              hipStream_t stream) {
    const float* preds    = (const float*)d_in[0];
    const float* features = (const float*)d_in[1];
    const int*   labels   = (const int*)d_in[2];
    const float* centers  = (const float*)d_in[3];
    float* out = (float*)d_out;

    char* ws = (char*)d_ws;
    float* updp   = (float*)ws;                          // NBLK*NC*DD f (11.1 MB)
    int*   hpartT = (int*)(ws + (size_t)NBLK * NC * DD * 4);   // NC*NBLK ints
    float* lossp  = (float*)(ws + (size_t)NBLK * NC * DD * 4
                                + (size_t)NC * NBLK * 4);      // NBLK floats

    k_fused<<<NBLK, 512, 0, stream>>>((const float4*)preds, labels, features,
                                      updp, hpartT, lossp, out);
    k_reduce<<<NC * 4 + 1, 256, 0, stream>>>(updp, lossp, centers, hpartT, out);
}